// Round 1
// baseline (306.026 us; speedup 1.0000x reference)
//
#include <hip/hip_runtime.h>
#include <math.h>

#define NN   512
#define NBLK 512

// smearing constants
#define START 0.006737946999085467f            // exp(-5)
#define STEP  ((1.0f - START) * (1.0f/15.0f))  // linspace step
#define SB    (0.125f * (1.0f - START))
#define BETA  (1.0f/(SB*SB))
#define LOG2E 1.4426950408889634f
#define NB    (-(BETA)*LOG2E)                  // exp(-beta t^2) = exp2(NB t^2)

// ===========================================================================
// R11: single persistent kernel. grid 512 x 256thr = 2 blocks/CU guaranteed
// co-resident (53.4 KB LDS, ~150 VGPR <= 256), so hand-rolled agent-scope
// grid barriers replace the 4 inter-kernel drains of the 5-kernel pipeline.
//  - phase 0: W transpose (old k0), 2 rows/block
//  - phase A: old k1a for units bid and bid+512 (same ib, jc and jc+4)
//  - phase B: old k1b, i = bid
//  - phase C: old k2a for the same two units, REUSING the LDS G/lP computed
//             in phase A (the whole second smearing pass is deleted)
//  - phase D: old k2b, i = bid
// Both heavy j-loops get 2-deep K/Q register prefetch (R9's spill trap was
// the __launch_bounds__ ",3" VGPR clamp, not the prefetch itself).
// All fma orders identical to R10 -> bitwise-identical output.
// ===========================================================================

__device__ __forceinline__ void gbar(unsigned* cnt, int k)
{
    __syncthreads();
    if (threadIdx.x == 0) {
        __threadfence();
        __hip_atomic_fetch_add(&cnt[k], 1u, __ATOMIC_RELEASE, __HIP_MEMORY_SCOPE_AGENT);
        while (__hip_atomic_load(&cnt[k], __ATOMIC_RELAXED, __HIP_MEMORY_SCOPE_AGENT) < (unsigned)NBLK)
            __builtin_amdgcn_s_sleep(8);
        __threadfence();
    }
    __syncthreads();
}

__device__ __forceinline__ void dot16(
    float4 g0, float4 g1, float4 g2, float4 g3,
    float4 ka, float4 kb, float4 kc, float4 kd,
    float4 qa, float4 qb, float4 qc, float4 qd,
    float& tk, float& tq)
{
    tk = g0.x*ka.x; tq = g0.x*qa.x;
    tk = fmaf(g0.y,ka.y,tk); tq = fmaf(g0.y,qa.y,tq);
    tk = fmaf(g0.z,ka.z,tk); tq = fmaf(g0.z,qa.z,tq);
    tk = fmaf(g0.w,ka.w,tk); tq = fmaf(g0.w,qa.w,tq);
    tk = fmaf(g1.x,kb.x,tk); tq = fmaf(g1.x,qb.x,tq);
    tk = fmaf(g1.y,kb.y,tk); tq = fmaf(g1.y,qb.y,tq);
    tk = fmaf(g1.z,kb.z,tk); tq = fmaf(g1.z,qb.z,tq);
    tk = fmaf(g1.w,kb.w,tk); tq = fmaf(g1.w,qb.w,tq);
    tk = fmaf(g2.x,kc.x,tk); tq = fmaf(g2.x,qc.x,tq);
    tk = fmaf(g2.y,kc.y,tk); tq = fmaf(g2.y,qc.y,tq);
    tk = fmaf(g2.z,kc.z,tk); tq = fmaf(g2.z,qc.z,tq);
    tk = fmaf(g2.w,kc.w,tk); tq = fmaf(g2.w,qc.w,tq);
    tk = fmaf(g3.x,kd.x,tk); tq = fmaf(g3.x,qd.x,tq);
    tk = fmaf(g3.y,kd.y,tk); tq = fmaf(g3.y,qd.y,tq);
    tk = fmaf(g3.z,kd.z,tk); tq = fmaf(g3.z,qd.z,tq);
    tk = fmaf(g3.w,kd.w,tk); tq = fmaf(g3.w,qd.w,tq);
}

__global__ __launch_bounds__(256) void mega(
    const float* __restrict__ x,
    const float* __restrict__ W,
    const float* __restrict__ W1,
    const float* __restrict__ b1,
    const float* __restrict__ W2,
    const float* __restrict__ W3,
    const float* __restrict__ b3,
    const float* __restrict__ W4,
    const float* __restrict__ b4,
    float* __restrict__ Wt,
    float* __restrict__ part1,
    float* __restrict__ part2,
    float* __restrict__ att2t,
    float* __restrict__ out,
    unsigned* __restrict__ cnt)
{
    __shared__ __align__(16) float  lG[2][4][64][16];   // 32 KB, persists A->C
    __shared__ float4               lP[2][4][64];       //  8 KB, persists A->C
    __shared__ float                s_part[4][16][38];  // 9.5 KB (stride 38: c*38%32 distinct)
    __shared__ float                s_red[144];         // B uses [0:96], D uses all
    __shared__ float                s_att[256];
    __shared__ float                s_z[16][16];
    __shared__ float                s_a1[16];

    const int bid = blockIdx.x;
    const int tid = threadIdx.x;

    // ---------------- phase 0: W transpose (old k0), 2 rows per block -----
    #pragma unroll
    for (int h = 0; h < 2; ++h) {
        const int row = bid + h*512;                   // 0..1023
        s_att[tid] = W[(size_t)row*256 + tid];
        __syncthreads();
        const int tc = tid >> 4, tr = tid & 15;
        Wt[(size_t)row*256 + tid] = s_att[tr*16 + tc]; // Wt[row][c][r]
        __syncthreads();
    }
    gbar(cnt, 0);

    // ---------------- common geometry ------------------------------------
    const int ib  = bid & 127, jcb = bid >> 7;         // units: (ib, jcb) and (ib, jcb+4)
    const int i0  = ib * 4;
    const int c   = tid & 15, js = tid >> 4;
    const int lane = tid & 63, wv = tid >> 6;

    // ---------------- phase A prologue: G + d for BOTH units -------------
    {
        const int pi = tid >> 6, pj = tid & 63;
        const float xi0 = x[(i0+pi)*3+0], xi1 = x[(i0+pi)*3+1], xi2 = x[(i0+pi)*3+2];
        #pragma unroll
        for (int un = 0; un < 2; ++un) {
            const int jg = (jcb + 4*un)*64 + pj;
            float d0 = xi0 - x[jg*3+0];
            float d1 = xi1 - x[jg*3+1];
            float d2 = xi2 - x[jg*3+2];
            float nsq = fmaf(d0,d0, fmaf(d1,d1, fmaf(d2,d2, 1e-6f)));
            float rs  = __builtin_amdgcn_rsqf(nsq);
            float nrm = nsq * rs;
            float inv = rs * rs;
            float cutv = 0.f;
            if (nrm < 5.0f) cutv = 0.5f*(__cosf(nrm*0.6283185307179586f)+1.0f);
            float en = exp2f(-LOG2E * nrm);
            lP[un][pi][pj] = make_float4(d0*inv, d1*inv, d2*inv, 0.f);
            float4* dst = reinterpret_cast<float4*>(&lG[un][pi][pj][0]);
            #pragma unroll
            for (int rq = 0; rq < 4; ++rq) {
                float t0 = en - (START + STEP*(float)(4*rq+0));
                float t1 = en - (START + STEP*(float)(4*rq+1));
                float t2 = en - (START + STEP*(float)(4*rq+2));
                float t3 = en - (START + STEP*(float)(4*rq+3));
                dst[rq] = make_float4(cutv*exp2f(NB*t0*t0), cutv*exp2f(NB*t1*t1),
                                      cutv*exp2f(NB*t2*t2), cutv*exp2f(NB*t3*t3));
            }
        }
    }
    __syncthreads();

    // ---------------- phase A: old k1a main loop, both units -------------
    #pragma unroll 1
    for (int un = 0; un < 2; ++un) {
        const int jc = jcb + 4*un;
        float acc[24];
        #pragma unroll
        for (int v = 0; v < 24; ++v) acc[v] = 0.f;

        const float4* Kp = reinterpret_cast<const float4*>(Wt + (size_t)(jc*64 + js)*256 + c*16);
        const float4* Qp = reinterpret_cast<const float4*>(Wt + (size_t)NN*256 + (size_t)(jc*64 + js)*256 + c*16);
        float4 ka = Kp[0], kb = Kp[1], kc = Kp[2], kd = Kp[3];
        float4 qa = Qp[0], qb = Qp[1], qc = Qp[2], qd = Qp[3];

        #pragma unroll 1
        for (int t = 0; t < 4; ++t) {
            float4 nka, nkb, nkc, nkd, nqa, nqb, nqc, nqd;
            if (t < 3) {                               // 2-deep prefetch (rows +16)
                const float4* Kn = Kp + (size_t)(t+1)*16*64;
                const float4* Qn = Qp + (size_t)(t+1)*16*64;
                nka = Kn[0]; nkb = Kn[1]; nkc = Kn[2]; nkd = Kn[3];
                nqa = Qn[0]; nqb = Qn[1]; nqc = Qn[2]; nqd = Qn[3];
            }
            const int jl = js + 16*t;
            #pragma unroll
            for (int i = 0; i < 4; ++i) {
                const float4* gp = reinterpret_cast<const float4*>(&lG[un][i][jl][0]);
                float tk, tq;
                dot16(gp[0], gp[1], gp[2], gp[3], ka,kb,kc,kd, qa,qb,qc,qd, tk, tq);
                float4 dd = lP[un][i][jl];
                acc[i*6+0] = fmaf(tk, dd.x, acc[i*6+0]);
                acc[i*6+1] = fmaf(tk, dd.y, acc[i*6+1]);
                acc[i*6+2] = fmaf(tk, dd.z, acc[i*6+2]);
                acc[i*6+3] = fmaf(tq, dd.x, acc[i*6+3]);
                acc[i*6+4] = fmaf(tq, dd.y, acc[i*6+4]);
                acc[i*6+5] = fmaf(tq, dd.z, acc[i*6+5]);
            }
            if (t < 3) { ka=nka; kb=nkb; kc=nkc; kd=nkd; qa=nqa; qb=nqb; qc=nqc; qd=nqd; }
        }

        #pragma unroll
        for (int v = 0; v < 24; ++v) {
            float t2 = acc[v];
            t2 += __shfl_xor(t2, 16);
            t2 += __shfl_xor(t2, 32);
            if (lane < 16) s_part[wv][c][v] = t2;
        }
        __syncthreads();

        for (int v = tid; v < 384; v += 256) {
            int i = v / 96, o = v - i*96;
            int kq = o / 48, rem = o - kq*48;
            int b = rem >> 4, c2 = rem & 15;
            int f = i*6 + kq*3 + b;
            float sum = s_part[0][c2][f] + s_part[1][c2][f]
                      + s_part[2][c2][f] + s_part[3][c2][f];
            part1[(i0+i)*768 + jc*96 + o] = sum;
        }
        __syncthreads();                                // s_part reuse by unit 2
    }
    gbar(cnt, 1);

    // ---------------- phase B: old k1b, i = bid --------------------------
    {
        const int i = bid;
        if (tid < 96) {
            const float* p = part1 + i*768 + tid;
            float s = 0.f;
            #pragma unroll
            for (int k = 0; k < 8; ++k) s += p[k*96];
            s_red[tid] = s;
        }
        __syncthreads();

        {
            int h = tid >> 4, g = tid & 15;
            s_att[tid] = s_red[     h]*s_red[48+     g]
                       + s_red[16 + h]*s_red[48+16 + g]
                       + s_red[32 + h]*s_red[48+32 + g];
        }
        __syncthreads();

        {
            int h = tid & 15, seg = tid >> 4;
            const float* w1 = W1 + h*256 + seg*16;
            const float* a  = s_att + seg*16;
            float p = 0.f;
            #pragma unroll
            for (int k = 0; k < 16; ++k) p = fmaf(a[k], w1[k], p);
            s_z[seg][h] = p;
        }
        __syncthreads();

        if (tid < 16) {
            float z = b1[tid];
            #pragma unroll
            for (int seg = 0; seg < 16; ++seg) z += s_z[seg][tid];
            s_a1[tid] = z / (1.0f + __expf(-z));
        }
        __syncthreads();

        float a1[16];
        #pragma unroll
        for (int cc = 0; cc < 16; ++cc) a1[cc] = s_a1[cc];
        #pragma unroll
        for (int p = 0; p < 4; ++p) {
            int o = tid + p*256;
            const float4* w2 = reinterpret_cast<const float4*>(W2 + o*16);
            float4 wa = w2[0], wb = w2[1], wc = w2[2], wd = w2[3];
            float accv = wa.x*a1[0] + wa.y*a1[1] + wa.z*a1[2] + wa.w*a1[3]
                       + wb.x*a1[4] + wb.y*a1[5] + wb.z*a1[6] + wb.w*a1[7]
                       + wc.x*a1[8] + wc.y*a1[9] + wc.z*a1[10]+ wc.w*a1[11]
                       + wd.x*a1[12]+ wd.y*a1[13]+ wd.z*a1[14]+ wd.w*a1[15];
            att2t[i*1024 + ((o>>8)*256) + ((o&15)*16) + ((o>>4)&15)] = accv;
        }
    }
    gbar(cnt, 2);

    // ---------------- phase C: old k2a, both units, G/lP REUSED ----------
    #pragma unroll 1
    for (int un = 0; un < 2; ++un) {
        const int jc = jcb + 4*un;
        float acc[36];                                  // 24 main + 12 S (r=c)
        #pragma unroll
        for (int v = 0; v < 36; ++v) acc[v] = 0.f;

        const float4* Kp = reinterpret_cast<const float4*>(att2t + (size_t)(jc*64 + js)*1024 + 512 + c*16);
        const float4* Qp = reinterpret_cast<const float4*>(att2t + (size_t)(jc*64 + js)*1024 + 768 + c*16);
        float4 ka = Kp[0], kb = Kp[1], kc = Kp[2], kd = Kp[3];
        float4 qa = Qp[0], qb = Qp[1], qc = Qp[2], qd = Qp[3];

        #pragma unroll 1
        for (int t = 0; t < 4; ++t) {
            float4 nka, nkb, nkc, nkd, nqa, nqb, nqc, nqd;
            if (t < 3) {                               // rows +16, stride 1024 floats
                const float4* Kn = Kp + (size_t)(t+1)*16*256;
                const float4* Qn = Qp + (size_t)(t+1)*16*256;
                nka = Kn[0]; nkb = Kn[1]; nkc = Kn[2]; nkd = Kn[3];
                nqa = Qn[0]; nqb = Qn[1]; nqc = Qn[2]; nqd = Qn[3];
            }
            const int jl = js + 16*t;
            #pragma unroll
            for (int i = 0; i < 4; ++i) {
                const float4* gp = reinterpret_cast<const float4*>(&lG[un][i][jl][0]);
                float tk, tq;
                dot16(gp[0], gp[1], gp[2], gp[3], ka,kb,kc,kd, qa,qb,qc,qd, tk, tq);
                float4 dd = lP[un][i][jl];
                acc[i*6+0] = fmaf(tk, dd.x, acc[i*6+0]);
                acc[i*6+1] = fmaf(tk, dd.y, acc[i*6+1]);
                acc[i*6+2] = fmaf(tk, dd.z, acc[i*6+2]);
                acc[i*6+3] = fmaf(tq, dd.x, acc[i*6+3]);
                acc[i*6+4] = fmaf(tq, dd.y, acc[i*6+4]);
                acc[i*6+5] = fmaf(tq, dd.z, acc[i*6+5]);
                float gc = lG[un][i][jl][c];            // this lane's r=c for S
                acc[24+i*3+0] = fmaf(gc, dd.x, acc[24+i*3+0]);
                acc[24+i*3+1] = fmaf(gc, dd.y, acc[24+i*3+1]);
                acc[24+i*3+2] = fmaf(gc, dd.z, acc[24+i*3+2]);
            }
            if (t < 3) { ka=nka; kb=nkb; kc=nkc; kd=nkd; qa=nqa; qb=nqb; qc=nqc; qd=nqd; }
        }

        #pragma unroll
        for (int v = 0; v < 36; ++v) {
            float t2 = acc[v];
            t2 += __shfl_xor(t2, 16);
            t2 += __shfl_xor(t2, 32);
            if (lane < 16) s_part[wv][c][v] = t2;
        }
        __syncthreads();

        for (int v = tid; v < 576; v += 256) {
            int i = v / 144, o = v - i*144;
            int c2, f;
            if (o < 96) {
                int kq = o / 48, rem = o - kq*48;
                int b = rem >> 4; c2 = rem & 15;
                f = i*6 + kq*3 + b;
            } else {
                int oS = o - 96;
                int r = oS / 3, b = oS - r*3;
                c2 = r;
                f = 24 + i*3 + b;
            }
            float sum = s_part[0][c2][f] + s_part[1][c2][f]
                      + s_part[2][c2][f] + s_part[3][c2][f];
            part2[(i0+i)*1152 + jc*144 + o] = sum;
        }
        __syncthreads();                                // s_part reuse by unit 2
    }
    gbar(cnt, 3);

    // ---------------- phase D: old k2b, i = bid --------------------------
    {
        const int i = bid;
        if (tid < 144) {
            const float* p = part2 + i*1152 + tid;
            float s = 0.f;
            #pragma unroll
            for (int k = 0; k < 8; ++k) s += p[k*144];
            s_red[tid] = s;
        }
        __syncthreads();

        if (tid < 96) {                  // left-term: bkq[c,b] += sum_r left[r,c]*S[r,b]
            int kq = tid / 48, rem = tid - kq*48;
            int b = rem >> 4, cc = rem & 15;
            const float4* lrow = reinterpret_cast<const float4*>(att2t + i*1024 + kq*256 + cc*16);
            float4 A = lrow[0], B = lrow[1], C = lrow[2], D = lrow[3];
            float add = 0.f;
            add = fmaf(A.x, s_red[96+ 0*3+b], add);
            add = fmaf(A.y, s_red[96+ 1*3+b], add);
            add = fmaf(A.z, s_red[96+ 2*3+b], add);
            add = fmaf(A.w, s_red[96+ 3*3+b], add);
            add = fmaf(B.x, s_red[96+ 4*3+b], add);
            add = fmaf(B.y, s_red[96+ 5*3+b], add);
            add = fmaf(B.z, s_red[96+ 6*3+b], add);
            add = fmaf(B.w, s_red[96+ 7*3+b], add);
            add = fmaf(C.x, s_red[96+ 8*3+b], add);
            add = fmaf(C.y, s_red[96+ 9*3+b], add);
            add = fmaf(C.z, s_red[96+10*3+b], add);
            add = fmaf(C.w, s_red[96+11*3+b], add);
            add = fmaf(D.x, s_red[96+12*3+b], add);
            add = fmaf(D.y, s_red[96+13*3+b], add);
            add = fmaf(D.z, s_red[96+14*3+b], add);
            add = fmaf(D.w, s_red[96+15*3+b], add);
            s_red[tid] += add;
        }
        __syncthreads();

        {
            int h = tid >> 4, g = tid & 15;
            s_att[tid] = s_red[     h]*s_red[48+     g]
                       + s_red[16 + h]*s_red[48+16 + g]
                       + s_red[32 + h]*s_red[48+32 + g];
        }
        __syncthreads();

        {
            int h = tid & 15, seg = tid >> 4;
            const float* w3 = W3 + h*256 + seg*16;
            const float* a  = s_att + seg*16;
            float p = 0.f;
            #pragma unroll
            for (int k = 0; k < 16; ++k) p = fmaf(a[k], w3[k], p);
            s_z[seg][h] = p;
        }
        __syncthreads();

        if (tid < 16) {
            float z = b3[tid];
            #pragma unroll
            for (int seg = 0; seg < 16; ++seg) z += s_z[seg][tid];
            s_a1[tid] = z / (1.0f + __expf(-z));
        }
        __syncthreads();

        if (tid == 0) {
            float accv = b4[0];
            #pragma unroll
            for (int cc = 0; cc < 16; ++cc) accv = fmaf(s_a1[cc], W4[cc], accv);
            out[i] = accv;
        }
    }
}

extern "C" void kernel_launch(void* const* d_in, const int* in_sizes, int n_in,
                              void* d_out, int out_size, void* d_ws, size_t ws_size,
                              hipStream_t stream) {
    (void)in_sizes; (void)n_in; (void)out_size; (void)ws_size;
    const float* x  = (const float*)d_in[0];
    const float* W  = (const float*)d_in[1];
    const float* W1 = (const float*)d_in[2];
    const float* b1 = (const float*)d_in[3];
    const float* W2 = (const float*)d_in[4];
    const float* W3 = (const float*)d_in[5];
    const float* b3 = (const float*)d_in[6];
    const float* W4 = (const float*)d_in[7];
    const float* b4 = (const float*)d_in[8];

    float* att2t = (float*)d_ws;             // 512*1024
    float* part1 = att2t + 512*1024;         // 512*768
    float* part2 = part1 + 512*768;          // 512*1152
    float* Wt    = part2 + 512*1152;         // 2*512*256
    unsigned* cnt = (unsigned*)(Wt + 2*512*256);  // 4 barrier counters
    float* out   = (float*)d_out;

    hipMemsetAsync(cnt, 0, 4*sizeof(unsigned), stream);
    mega<<<NBLK, 256, 0, stream>>>(x, W, W1, b1, W2, W3, b3, W4, b4,
                                   Wt, part1, part2, att2t, out, cnt);
}

// Round 2
// 120.913 us; speedup vs baseline: 2.5310x; 2.5310x over previous
//
#include <hip/hip_runtime.h>
#include <math.h>

#define NN 512

// smearing constants
#define START 0.006737946999085467f            // exp(-5)
#define STEP  ((1.0f - START) * (1.0f/15.0f))  // linspace step
#define SB    (0.125f * (1.0f - START))
#define BETA  (1.0f/(SB*SB))
#define LOG2E 1.4426950408889634f
#define NB    (-(BETA)*LOG2E)                  // exp(-beta t^2) = exp2(NB t^2)

// ===========================================================================
// R12 = R10 (proven 118 us) + 1-deep K/Q register prefetch in the k1a/k2a
// t-loops (load tile t+1's 8 float4 before computing tile t) to hide L2
// latency. R11's fused build proved this prefetch fits in 120 VGPR (no
// spill). Grid-barrier fusion is permanently abandoned: agent-scope fences
// writeback+invalidate per-XCD L2 on gfx950, demoting all Wt/att2t reuse
// to IC/HBM latency (R11: 250 us @ 5.6% VALUBusy).
// ===========================================================================

__global__ __launch_bounds__(256) void k0(const float* __restrict__ W,
                                          float* __restrict__ Wt)
{
    __shared__ float ldsb[256];
    const int row = blockIdx.x;                // (a,j) 0..1023
    ldsb[threadIdx.x] = W[(size_t)row*256 + threadIdx.x];
    __syncthreads();
    const int c = threadIdx.x >> 4, r = threadIdx.x & 15;
    Wt[(size_t)row*256 + threadIdx.x] = ldsb[r*16 + c];   // Wt[row][c][r]
}

__device__ __forceinline__ void dot16(
    float4 g0, float4 g1, float4 g2, float4 g3,
    float4 ka, float4 kb, float4 kc, float4 kd,
    float4 qa, float4 qb, float4 qc, float4 qd,
    float& tk, float& tq)
{
    tk = g0.x*ka.x; tq = g0.x*qa.x;
    tk = fmaf(g0.y,ka.y,tk); tq = fmaf(g0.y,qa.y,tq);
    tk = fmaf(g0.z,ka.z,tk); tq = fmaf(g0.z,qa.z,tq);
    tk = fmaf(g0.w,ka.w,tk); tq = fmaf(g0.w,qa.w,tq);
    tk = fmaf(g1.x,kb.x,tk); tq = fmaf(g1.x,qb.x,tq);
    tk = fmaf(g1.y,kb.y,tk); tq = fmaf(g1.y,qb.y,tq);
    tk = fmaf(g1.z,kb.z,tk); tq = fmaf(g1.z,qb.z,tq);
    tk = fmaf(g1.w,kb.w,tk); tq = fmaf(g1.w,qb.w,tq);
    tk = fmaf(g2.x,kc.x,tk); tq = fmaf(g2.x,qc.x,tq);
    tk = fmaf(g2.y,kc.y,tk); tq = fmaf(g2.y,qc.y,tq);
    tk = fmaf(g2.z,kc.z,tk); tq = fmaf(g2.z,qc.z,tq);
    tk = fmaf(g2.w,kc.w,tk); tq = fmaf(g2.w,qc.w,tq);
    tk = fmaf(g3.x,kd.x,tk); tq = fmaf(g3.x,qd.x,tq);
    tk = fmaf(g3.y,kd.y,tk); tq = fmaf(g3.y,qd.y,tq);
    tk = fmaf(g3.z,kd.z,tk); tq = fmaf(g3.z,qd.z,tq);
    tk = fmaf(g3.w,kd.w,tk); tq = fmaf(g3.w,qd.w,tq);
}

// ---------------------------------------------------------------------------
// k1a: stage-1 partials. part1[i][jc][96], 96 = kq*48 + b*16 + c.
// ---------------------------------------------------------------------------
__global__ __launch_bounds__(256) void k1a(const float* __restrict__ x,
                                           const float* __restrict__ Wt,
                                           float* __restrict__ part1)
{
    const int ib = blockIdx.x & 127, jc = blockIdx.x >> 7;
    const int i0 = ib * 4;
    const int tid = threadIdx.x;
    const int c = tid & 15, js = tid >> 4;
    const int lane = tid & 63, wv = tid >> 6;

    __shared__ float  lG[4][64][16];           // fp32 G
    __shared__ float4 lP[4][64];
    __shared__ float  s_part[4][16][26];

    // ---- phase 1: G + d for all (4 i) x (64 j), one (i,j) per thread ----
    {
        const int pi = tid >> 6, pj = tid & 63;
        const int jg = jc*64 + pj;
        const float xi0 = x[(i0+pi)*3+0], xi1 = x[(i0+pi)*3+1], xi2 = x[(i0+pi)*3+2];
        float d0 = xi0 - x[jg*3+0];
        float d1 = xi1 - x[jg*3+1];
        float d2 = xi2 - x[jg*3+2];
        float nsq = fmaf(d0,d0, fmaf(d1,d1, fmaf(d2,d2, 1e-6f)));
        float rs  = __builtin_amdgcn_rsqf(nsq);
        float nrm = nsq * rs;
        float inv = rs * rs;
        float cutv = 0.f;
        if (nrm < 5.0f) cutv = 0.5f*(__cosf(nrm*0.6283185307179586f)+1.0f);
        float en = exp2f(-LOG2E * nrm);
        lP[pi][pj] = make_float4(d0*inv, d1*inv, d2*inv, 0.f);
        float4* dst = reinterpret_cast<float4*>(&lG[pi][pj][0]);
        #pragma unroll
        for (int rq = 0; rq < 4; ++rq) {
            float t0 = en - (START + STEP*(float)(4*rq+0));
            float t1 = en - (START + STEP*(float)(4*rq+1));
            float t2 = en - (START + STEP*(float)(4*rq+2));
            float t3 = en - (START + STEP*(float)(4*rq+3));
            dst[rq] = make_float4(cutv*exp2f(NB*t0*t0), cutv*exp2f(NB*t1*t1),
                                  cutv*exp2f(NB*t2*t2), cutv*exp2f(NB*t3*t3));
        }
    }
    __syncthreads();                            // the ONLY main-loop barrier

    float acc[24];                              // i*6 + kq*3 + b
    #pragma unroll
    for (int v = 0; v < 24; ++v) acc[v] = 0.f;

    // K/Q pointers for this thread's base row (js), advancing 16 rows per t
    const float4* Kp = reinterpret_cast<const float4*>(Wt + (size_t)(jc*64 + js)*256 + c*16);
    const float4* Qp = reinterpret_cast<const float4*>(Wt + (size_t)NN*256 + (size_t)(jc*64 + js)*256 + c*16);
    float4 ka = Kp[0], kb = Kp[1], kc = Kp[2], kd = Kp[3];
    float4 qa = Qp[0], qb = Qp[1], qc = Qp[2], qd = Qp[3];

    #pragma unroll 1
    for (int t = 0; t < 4; ++t) {
        float4 nka, nkb, nkc, nkd, nqa, nqb, nqc, nqd;
        if (t < 3) {                            // prefetch rows +16 (stride 256 floats)
            const float4* Kn = Kp + (size_t)(t+1)*16*64;
            const float4* Qn = Qp + (size_t)(t+1)*16*64;
            nka = Kn[0]; nkb = Kn[1]; nkc = Kn[2]; nkd = Kn[3];
            nqa = Qn[0]; nqb = Qn[1]; nqc = Qn[2]; nqd = Qn[3];
        }
        const int jl = js + 16*t;

        #pragma unroll
        for (int i = 0; i < 4; ++i) {
            const float4* gp = reinterpret_cast<const float4*>(&lG[i][jl][0]);
            float tk, tq;
            dot16(gp[0], gp[1], gp[2], gp[3], ka,kb,kc,kd, qa,qb,qc,qd, tk, tq);
            float4 dd = lP[i][jl];
            acc[i*6+0] = fmaf(tk, dd.x, acc[i*6+0]);
            acc[i*6+1] = fmaf(tk, dd.y, acc[i*6+1]);
            acc[i*6+2] = fmaf(tk, dd.z, acc[i*6+2]);
            acc[i*6+3] = fmaf(tq, dd.x, acc[i*6+3]);
            acc[i*6+4] = fmaf(tq, dd.y, acc[i*6+4]);
            acc[i*6+5] = fmaf(tq, dd.z, acc[i*6+5]);
        }
        if (t < 3) { ka=nka; kb=nkb; kc=nkc; kd=nkd; qa=nqa; qb=nqb; qc=nqc; qd=nqd; }
    }

    #pragma unroll
    for (int v = 0; v < 24; ++v) {
        float t = acc[v];
        t += __shfl_xor(t, 16);
        t += __shfl_xor(t, 32);
        if (lane < 16) s_part[wv][c][v] = t;
    }
    __syncthreads();

    for (int v = tid; v < 384; v += 256) {
        int i = v / 96, o = v - i*96;
        int kq = o / 48, rem = o - kq*48;
        int b = rem >> 4, c2 = rem & 15;
        int f = i*6 + kq*3 + b;
        float sum = s_part[0][c2][f] + s_part[1][c2][f]
                  + s_part[2][c2][f] + s_part[3][c2][f];
        part1[(i0+i)*768 + jc*96 + o] = sum;
    }
}

// ---------------------------------------------------------------------------
// k1b: reduce 8 partials -> att1 -> silu(W1) -> att2 row (TRANSPOSED store).
// att2t[i][q2][c][r] = att2[i][q2*256 + r*16 + c]
// ---------------------------------------------------------------------------
__global__ __launch_bounds__(256) void k1b(const float* __restrict__ part1,
                                           const float* __restrict__ W1,
                                           const float* __restrict__ b1,
                                           const float* __restrict__ W2,
                                           float* __restrict__ att2t)
{
    const int i = blockIdx.x;
    const int tid = threadIdx.x;
    __shared__ float s_bkq[96];
    __shared__ float s_att[256];
    __shared__ float s_z[16][16];
    __shared__ float s_a1[16];

    if (tid < 96) {
        const float* p = part1 + i*768 + tid;
        float s = 0.f;
        #pragma unroll
        for (int k = 0; k < 8; ++k) s += p[k*96];
        s_bkq[tid] = s;
    }
    __syncthreads();

    {
        int h = tid >> 4, g = tid & 15;
        s_att[tid] = s_bkq[     h]*s_bkq[48+     g]
                   + s_bkq[16 + h]*s_bkq[48+16 + g]
                   + s_bkq[32 + h]*s_bkq[48+32 + g];
    }
    __syncthreads();

    {
        int h = tid & 15, seg = tid >> 4;
        const float* w1 = W1 + h*256 + seg*16;
        const float* a  = s_att + seg*16;
        float p = 0.f;
        #pragma unroll
        for (int k = 0; k < 16; ++k) p = fmaf(a[k], w1[k], p);
        s_z[seg][h] = p;
    }
    __syncthreads();

    if (tid < 16) {
        float z = b1[tid];
        #pragma unroll
        for (int seg = 0; seg < 16; ++seg) z += s_z[seg][tid];
        s_a1[tid] = z / (1.0f + __expf(-z));
    }
    __syncthreads();

    float a1[16];
    #pragma unroll
    for (int cc = 0; cc < 16; ++cc) a1[cc] = s_a1[cc];
    #pragma unroll
    for (int p = 0; p < 4; ++p) {
        int o = tid + p*256;
        const float4* w2 = reinterpret_cast<const float4*>(W2 + o*16);
        float4 wa = w2[0], wb = w2[1], wc = w2[2], wd = w2[3];
        float accv = wa.x*a1[0] + wa.y*a1[1] + wa.z*a1[2] + wa.w*a1[3]
                   + wb.x*a1[4] + wb.y*a1[5] + wb.z*a1[6] + wb.w*a1[7]
                   + wc.x*a1[8] + wc.y*a1[9] + wc.z*a1[10]+ wc.w*a1[11]
                   + wd.x*a1[12]+ wd.y*a1[13]+ wd.z*a1[14]+ wd.w*a1[15];
        // transposed store: q2 = o>>8, r = (o>>4)&15, c = o&15
        att2t[i*1024 + ((o>>8)*256) + ((o&15)*16) + ((o>>4)&15)] = accv;
    }
}

// ---------------------------------------------------------------------------
// k2a: stage-3 right-term + S partials. part2[i][jc][144].
// ---------------------------------------------------------------------------
__global__ __launch_bounds__(256) void k2a(const float* __restrict__ x,
                                           const float* __restrict__ att2t,
                                           float* __restrict__ part2)
{
    const int ib = blockIdx.x & 127, jc = blockIdx.x >> 7;
    const int i0 = ib * 4;
    const int tid = threadIdx.x;
    const int c = tid & 15, js = tid >> 4;
    const int lane = tid & 63, wv = tid >> 6;

    __shared__ float  lG[4][64][16];
    __shared__ float4 lP[4][64];
    __shared__ float  s_part[4][16][38];

    {
        const int pi = tid >> 6, pj = tid & 63;
        const int jg = jc*64 + pj;
        const float xi0 = x[(i0+pi)*3+0], xi1 = x[(i0+pi)*3+1], xi2 = x[(i0+pi)*3+2];
        float d0 = xi0 - x[jg*3+0];
        float d1 = xi1 - x[jg*3+1];
        float d2 = xi2 - x[jg*3+2];
        float nsq = fmaf(d0,d0, fmaf(d1,d1, fmaf(d2,d2, 1e-6f)));
        float rs  = __builtin_amdgcn_rsqf(nsq);
        float nrm = nsq * rs;
        float inv = rs * rs;
        float cutv = 0.f;
        if (nrm < 5.0f) cutv = 0.5f*(__cosf(nrm*0.6283185307179586f)+1.0f);
        float en = exp2f(-LOG2E * nrm);
        lP[pi][pj] = make_float4(d0*inv, d1*inv, d2*inv, 0.f);
        float4* dst = reinterpret_cast<float4*>(&lG[pi][pj][0]);
        #pragma unroll
        for (int rq = 0; rq < 4; ++rq) {
            float t0 = en - (START + STEP*(float)(4*rq+0));
            float t1 = en - (START + STEP*(float)(4*rq+1));
            float t2 = en - (START + STEP*(float)(4*rq+2));
            float t3 = en - (START + STEP*(float)(4*rq+3));
            dst[rq] = make_float4(cutv*exp2f(NB*t0*t0), cutv*exp2f(NB*t1*t1),
                                  cutv*exp2f(NB*t2*t2), cutv*exp2f(NB*t3*t3));
        }
    }
    __syncthreads();

    float acc[36];                              // 24 main + 12 S (24+i*3+b, r=c)
    #pragma unroll
    for (int v = 0; v < 36; ++v) acc[v] = 0.f;

    const float4* Kp = reinterpret_cast<const float4*>(att2t + (size_t)(jc*64 + js)*1024 + 512 + c*16);
    const float4* Qp = reinterpret_cast<const float4*>(att2t + (size_t)(jc*64 + js)*1024 + 768 + c*16);
    float4 ka = Kp[0], kb = Kp[1], kc = Kp[2], kd = Kp[3];
    float4 qa = Qp[0], qb = Qp[1], qc = Qp[2], qd = Qp[3];

    #pragma unroll 1
    for (int t = 0; t < 4; ++t) {
        float4 nka, nkb, nkc, nkd, nqa, nqb, nqc, nqd;
        if (t < 3) {                            // prefetch rows +16 (stride 1024 floats)
            const float4* Kn = Kp + (size_t)(t+1)*16*256;
            const float4* Qn = Qp + (size_t)(t+1)*16*256;
            nka = Kn[0]; nkb = Kn[1]; nkc = Kn[2]; nkd = Kn[3];
            nqa = Qn[0]; nqb = Qn[1]; nqc = Qn[2]; nqd = Qn[3];
        }
        const int jl = js + 16*t;

        #pragma unroll
        for (int i = 0; i < 4; ++i) {
            const float4* gp = reinterpret_cast<const float4*>(&lG[i][jl][0]);
            float tk, tq;
            dot16(gp[0], gp[1], gp[2], gp[3], ka,kb,kc,kd, qa,qb,qc,qd, tk, tq);
            float4 dd = lP[i][jl];
            acc[i*6+0] = fmaf(tk, dd.x, acc[i*6+0]);
            acc[i*6+1] = fmaf(tk, dd.y, acc[i*6+1]);
            acc[i*6+2] = fmaf(tk, dd.z, acc[i*6+2]);
            acc[i*6+3] = fmaf(tq, dd.x, acc[i*6+3]);
            acc[i*6+4] = fmaf(tq, dd.y, acc[i*6+4]);
            acc[i*6+5] = fmaf(tq, dd.z, acc[i*6+5]);
            float gc = lG[i][jl][c];            // this lane's r=c for S
            acc[24+i*3+0] = fmaf(gc, dd.x, acc[24+i*3+0]);
            acc[24+i*3+1] = fmaf(gc, dd.y, acc[24+i*3+1]);
            acc[24+i*3+2] = fmaf(gc, dd.z, acc[24+i*3+2]);
        }
        if (t < 3) { ka=nka; kb=nkb; kc=nkc; kd=nkd; qa=nqa; qb=nqb; qc=nqc; qd=nqd; }
    }

    #pragma unroll
    for (int v = 0; v < 36; ++v) {
        float t = acc[v];
        t += __shfl_xor(t, 16);
        t += __shfl_xor(t, 32);
        if (lane < 16) s_part[wv][c][v] = t;
    }
    __syncthreads();

    for (int v = tid; v < 576; v += 256) {
        int i = v / 144, o = v - i*144;
        int c2, f;
        if (o < 96) {
            int kq = o / 48, rem = o - kq*48;
            int b = rem >> 4; c2 = rem & 15;
            f = i*6 + kq*3 + b;
        } else {
            int oS = o - 96;
            int r = oS / 3, b = oS - r*3;
            c2 = r;
            f = 24 + i*3 + b;
        }
        float sum = s_part[0][c2][f] + s_part[1][c2][f]
                  + s_part[2][c2][f] + s_part[3][c2][f];
        part2[(i0+i)*1152 + jc*144 + o] = sum;
    }
}

// ---------------------------------------------------------------------------
// k2b: reduce 8 partials + left-term (transposed att2t rows) -> out. Grid 512.
// ---------------------------------------------------------------------------
__global__ __launch_bounds__(256) void k2b(const float* __restrict__ att2t,
                                           const float* __restrict__ part2,
                                           const float* __restrict__ W3,
                                           const float* __restrict__ b3,
                                           const float* __restrict__ W4,
                                           const float* __restrict__ b4,
                                           float* __restrict__ out)
{
    const int i = blockIdx.x;
    const int tid = threadIdx.x;
    __shared__ float s_red[144];
    __shared__ float s_att[256];
    __shared__ float s_z[16][16];
    __shared__ float s_a1[16];

    if (tid < 144) {
        const float* p = part2 + i*1152 + tid;
        float s = 0.f;
        #pragma unroll
        for (int k = 0; k < 8; ++k) s += p[k*144];
        s_red[tid] = s;
    }
    __syncthreads();

    if (tid < 96) {                      // left-term: bkq[c,b] += sum_r left[r,c]*S[r,b]
        int kq = tid / 48, rem = tid - kq*48;
        int b = rem >> 4, cc = rem & 15;
        const float4* lrow = reinterpret_cast<const float4*>(att2t + i*1024 + kq*256 + cc*16);
        float4 A = lrow[0], B = lrow[1], C = lrow[2], D = lrow[3];
        float add = 0.f;
        add = fmaf(A.x, s_red[96+ 0*3+b], add);
        add = fmaf(A.y, s_red[96+ 1*3+b], add);
        add = fmaf(A.z, s_red[96+ 2*3+b], add);
        add = fmaf(A.w, s_red[96+ 3*3+b], add);
        add = fmaf(B.x, s_red[96+ 4*3+b], add);
        add = fmaf(B.y, s_red[96+ 5*3+b], add);
        add = fmaf(B.z, s_red[96+ 6*3+b], add);
        add = fmaf(B.w, s_red[96+ 7*3+b], add);
        add = fmaf(C.x, s_red[96+ 8*3+b], add);
        add = fmaf(C.y, s_red[96+ 9*3+b], add);
        add = fmaf(C.z, s_red[96+10*3+b], add);
        add = fmaf(C.w, s_red[96+11*3+b], add);
        add = fmaf(D.x, s_red[96+12*3+b], add);
        add = fmaf(D.y, s_red[96+13*3+b], add);
        add = fmaf(D.z, s_red[96+14*3+b], add);
        add = fmaf(D.w, s_red[96+15*3+b], add);
        s_red[tid] += add;
    }
    __syncthreads();

    {
        int h = tid >> 4, g = tid & 15;
        s_att[tid] = s_red[     h]*s_red[48+     g]
                   + s_red[16 + h]*s_red[48+16 + g]
                   + s_red[32 + h]*s_red[48+32 + g];
    }
    __syncthreads();

    {
        int h = tid & 15, seg = tid >> 4;
        const float* w3 = W3 + h*256 + seg*16;
        const float* a  = s_att + seg*16;
        float p = 0.f;
        #pragma unroll
        for (int k = 0; k < 16; ++k) p = fmaf(a[k], w3[k], p);
        s_z[seg][h] = p;
    }
    __syncthreads();

    if (tid < 16) {
        float z = b3[tid];
        #pragma unroll
        for (int seg = 0; seg < 16; ++seg) z += s_z[seg][tid];
        s_a1[tid] = z / (1.0f + __expf(-z));
    }
    __syncthreads();

    if (tid == 0) {
        float accv = b4[0];
        #pragma unroll
        for (int cc = 0; cc < 16; ++cc) accv = fmaf(s_a1[cc], W4[cc], accv);
        out[i] = accv;
    }
}

extern "C" void kernel_launch(void* const* d_in, const int* in_sizes, int n_in,
                              void* d_out, int out_size, void* d_ws, size_t ws_size,
                              hipStream_t stream) {
    (void)in_sizes; (void)n_in; (void)out_size; (void)ws_size;
    const float* x  = (const float*)d_in[0];
    const float* W  = (const float*)d_in[1];
    const float* W1 = (const float*)d_in[2];
    const float* b1 = (const float*)d_in[3];
    const float* W2 = (const float*)d_in[4];
    const float* W3 = (const float*)d_in[5];
    const float* b3 = (const float*)d_in[6];
    const float* W4 = (const float*)d_in[7];
    const float* b4 = (const float*)d_in[8];

    float* att2t = (float*)d_ws;             // 512*1024
    float* part1 = att2t + 512*1024;         // 512*768
    float* part2 = part1 + 512*768;          // 512*1152
    float* Wt    = part2 + 512*1152;         // 2*512*256
    float* out   = (float*)d_out;

    k0 <<<1024, 256, 0, stream>>>(W, Wt);
    k1a<<<1024, 256, 0, stream>>>(x, Wt, part1);
    k1b<<< 512, 256, 0, stream>>>(part1, W1, b1, W2, att2t);
    k2a<<<1024, 256, 0, stream>>>(x, att2t, part2);
    k2b<<< 512, 256, 0, stream>>>(att2t, part2, W3, b3, W4, b4, out);
}